// Round 4
// baseline (946.708 us; speedup 1.0000x reference)
//
#include <hip/hip_runtime.h>

using u16 = unsigned short;

typedef __bf16 bf16x8 __attribute__((ext_vector_type(8)));
typedef float  f32x4  __attribute__((ext_vector_type(4)));

__device__ __forceinline__ float b2f(u16 u) {
    union { unsigned int i; float f; } c; c.i = ((unsigned int)u) << 16; return c.f;
}
__device__ __forceinline__ u16 f2b(float f) {
    union { float f; unsigned int i; } c; c.f = f;
    unsigned int i = c.i;
    return (u16)((i + 0x7FFFu + ((i >> 16) & 1u)) >> 16);
}

#define AS1 __attribute__((address_space(1)))
#define AS3 __attribute__((address_space(3)))
__device__ __forceinline__ void glds16(const u16* g, u16* l) {
    __builtin_amdgcn_global_load_lds((const AS1 void*)(const void*)g,
                                     (AS3 void*)(void*)l, 16, 0, 0);
}

// ---------------------------------------------------------------------------
// Batched transpose + convert f32 -> bf16: in[b][R][C] f32 -> out[b][C][R] bf16
// ---------------------------------------------------------------------------
__global__ void btrans_f2b(const float* __restrict__ in, u16* __restrict__ out, int R, int C) {
    __shared__ u16 tile[32][33];
    const int c0 = blockIdx.x * 32, r0 = blockIdx.y * 32;
    const size_t base = (size_t)blockIdx.z * R * C;
    const int tx = threadIdx.x, ty = threadIdx.y;
    #pragma unroll
    for (int i = ty; i < 32; i += 8) {
        int r = r0 + i, c = c0 + tx;
        tile[i][tx] = (r < R && c < C) ? f2b(in[base + (size_t)r * C + c]) : (u16)0;
    }
    __syncthreads();
    #pragma unroll
    for (int i = ty; i < 32; i += 8) {
        int c = c0 + i, r = r0 + tx;
        if (c < C && r < R) out[base + (size_t)c * R + r] = tile[tx][i];
    }
}

// Batched transpose + convert bf16 -> f32: in[b][R][C] bf16 -> out[b][C][R] f32
__global__ void btrans_b2f(const u16* __restrict__ in, float* __restrict__ out, int R, int C) {
    __shared__ u16 tile[32][33];
    const int c0 = blockIdx.x * 32, r0 = blockIdx.y * 32;
    const size_t base = (size_t)blockIdx.z * R * C;
    const int tx = threadIdx.x, ty = threadIdx.y;
    #pragma unroll
    for (int i = ty; i < 32; i += 8) {
        int r = r0 + i, c = c0 + tx;
        tile[i][tx] = (r < R && c < C) ? in[base + (size_t)r * C + c] : (u16)0;
    }
    __syncthreads();
    #pragma unroll
    for (int i = ty; i < 32; i += 8) {
        int c = c0 + i, r = r0 + tx;
        if (c < C && r < R) out[base + (size_t)c * R + r] = b2f(tile[tx][i]);
    }
}

// ---------------------------------------------------------------------------
// m97-style GEMM: C[M,N] = epilogue(A[M,K] @ BT[N,K]^T + bias)   (A,BT,C bf16)
// 128x128 block tile, BK=32, 4 waves (2x2), each wave 4x4 tiles of 16x16x32.
// EPI: 0 = bias only (QKV)
//      1 = bias + residual(R0 bf16) + RepBN
//      2 = bias + SpatialSiLU (saw/sab indexed by (row0+row)/196)
// Epilogue parameter vectors are f32 (native input storage).
// ---------------------------------------------------------------------------
template<int EPI>
__launch_bounds__(256)
__global__ void gemm_bt(const u16* __restrict__ A, const u16* __restrict__ BT,
                        const float* __restrict__ bias, u16* __restrict__ C,
                        int M, int N, int K, int row0,
                        const u16* __restrict__ R0,
                        const float* __restrict__ g, const float* __restrict__ be,
                        const float* __restrict__ rmv, const float* __restrict__ rvv,
                        const float* __restrict__ alpha,
                        const float* __restrict__ saw, const float* __restrict__ sab) {
    __shared__ __align__(16) u16 ALds[128 * 32];
    __shared__ __align__(16) u16 BLds[128 * 32];
    const int tid  = threadIdx.x;
    const int wave = tid >> 6, lane = tid & 63;
    const int wm = wave >> 1, wn = wave & 1;
    const int quad = lane >> 4, l16 = lane & 15;
    const int m0 = blockIdx.y * 128, n0 = blockIdx.x * 128;

    // staging: chunk = wave*2+c covers rows chunk*16..+15; lane -> row=lane/4, col=(lane&3)*8
    const int srow = lane >> 2;
    const int scol = (lane & 3) * 8;
    const u16* aG0 = A  + (size_t)(m0 + wave * 32 + srow) * K + scol;
    const u16* aG1 = aG0 + (size_t)16 * K;
    const u16* bG0 = BT + (size_t)(n0 + wave * 32 + srow) * K + scol;
    const u16* bG1 = bG0 + (size_t)16 * K;
    u16* aL0 = &ALds[(wave * 2    ) * 512];
    u16* aL1 = &ALds[(wave * 2 + 1) * 512];
    u16* bL0 = &BLds[(wave * 2    ) * 512];
    u16* bL1 = &BLds[(wave * 2 + 1) * 512];

    f32x4 acc[4][4] = {};

    for (int k0 = 0; k0 < K; k0 += 32) {
        glds16(aG0, aL0); glds16(aG1, aL1);
        glds16(bG0, bL0); glds16(bG1, bL1);
        aG0 += 32; aG1 += 32; bG0 += 32; bG1 += 32;
        __syncthreads();
        bf16x8 af[4], bfr[4];
        #pragma unroll
        for (int i = 0; i < 4; i++)
            af[i] = *(const bf16x8*)&ALds[(wm * 64 + i * 16 + l16) * 32 + quad * 8];
        #pragma unroll
        for (int j = 0; j < 4; j++)
            bfr[j] = *(const bf16x8*)&BLds[(wn * 64 + j * 16 + l16) * 32 + quad * 8];
        #pragma unroll
        for (int i = 0; i < 4; i++)
            #pragma unroll
            for (int j = 0; j < 4; j++)
                acc[i][j] = __builtin_amdgcn_mfma_f32_16x16x32_bf16(af[i], bfr[j], acc[i][j], 0, 0, 0);
        __syncthreads();
    }

    float alphav = 0.f;
    if (EPI == 1) alphav = alpha[0];

    #pragma unroll
    for (int i = 0; i < 4; i++) {
        const int rowb = m0 + wm * 64 + i * 16 + quad * 4;
        #pragma unroll
        for (int r = 0; r < 4; r++) {
            const int row = rowb + r;
            float swv = 0.f, sbv = 0.f;
            if (EPI == 2) { int bidx = (row0 + row) / 196; swv = saw[bidx]; sbv = sab[bidx]; }
            #pragma unroll
            for (int j = 0; j < 4; j++) {
                const int col = n0 + wn * 64 + j * 16 + l16;
                float v = acc[i][j][r] + bias[col];
                const size_t off = (size_t)row * N + col;
                if (EPI == 0) {
                    C[off] = f2b(v);
                } else if (EPI == 1) {
                    float x  = v + b2f(R0[off]);
                    float sc = g[col] * rsqrtf(rvv[col] + 1e-5f);
                    float t  = (x - rmv[col]) * sc + be[col] + alphav * x;
                    C[off]  = f2b(t);
                } else { // EPI == 2
                    float w   = swv * v + sbv;
                    float out = v / (1.f + __expf(-w * v));
                    C[off] = f2b(out);
                }
            }
        }
    }
}

// ---------------------------------------------------------------------------
// VALU flash attention: one block per (local b, h). K,V in LDS (f32), one
// Q-row per thread, chunked online softmax. LDS reads are wave-broadcast.
// qkv layout (bf16): row = b*196+n (within chunk), col = s*256 + h*32 + d
// ---------------------------------------------------------------------------
__launch_bounds__(256)
__global__ void attn_kernel(const u16* __restrict__ qkv, u16* __restrict__ o) {
    __shared__ float Ks[196 * 32];
    __shared__ float Vs[196 * 32];
    const int tid = threadIdx.x;
    const int b = blockIdx.x >> 3, h = blockIdx.x & 7;
    const u16* base = qkv + (size_t)b * 196 * 768 + h * 32;

    for (int idx = tid; idx < 196 * 32; idx += 256) {
        int m = idx >> 5, d = idx & 31;
        Ks[idx] = b2f(base[(size_t)m * 768 + 256 + d]);
        Vs[idx] = b2f(base[(size_t)m * 768 + 512 + d]);
    }
    __syncthreads();

    if (tid < 196) {
        const u16* qp = base + (size_t)tid * 768;
        float q[32];
        #pragma unroll
        for (int d = 0; d < 32; d++) q[d] = b2f(qp[d]) * 0.17677669529663687f; // 1/sqrt(32)
        float accv[32];
        #pragma unroll
        for (int d = 0; d < 32; d++) accv[d] = 0.f;
        float mrun = -1e30f, lrun = 0.f;

        for (int mc = 0; mc < 196; mc += 14) {
            float sc[14];
            float cmax = -1e30f;
            #pragma unroll
            for (int t = 0; t < 14; t++) {
                const float* kr = &Ks[(mc + t) * 32];
                float s = 0.f;
                #pragma unroll
                for (int d = 0; d < 32; d++) s += q[d] * kr[d];
                sc[t] = s;
                cmax = fmaxf(cmax, s);
            }
            float newm = fmaxf(mrun, cmax);
            float corr = __expf(mrun - newm);
            lrun *= corr;
            #pragma unroll
            for (int d = 0; d < 32; d++) accv[d] *= corr;
            #pragma unroll
            for (int t = 0; t < 14; t++) {
                float p = __expf(sc[t] - newm);
                lrun += p;
                const float* vr = &Vs[(mc + t) * 32];
                #pragma unroll
                for (int d = 0; d < 32; d++) accv[d] += p * vr[d];
            }
            mrun = newm;
        }
        float inv = 1.f / lrun;
        u16* op = o + ((size_t)b * 196 + tid) * 256 + h * 32;
        #pragma unroll
        for (int d = 0; d < 32; d++) op[d] = f2b(accv[d] * inv);
    }
}

// ---------------------------------------------------------------------------
extern "C" void kernel_launch(void* const* d_in, const int* in_sizes, int n_in,
                              void* d_out, int out_size, void* d_ws, size_t ws_size,
                              hipStream_t stream) {
    // All inputs are float32 per the reference's setup_inputs().
    const float* x      = (const float*)d_in[0];
    const float* Wqkv   = (const float*)d_in[1];
    const float* bqkv   = (const float*)d_in[2];
    const float* Wproj  = (const float*)d_in[3];
    const float* bproj  = (const float*)d_in[4];
    const float* W1     = (const float*)d_in[5];
    const float* b1     = (const float*)d_in[6];
    const float* W2     = (const float*)d_in[7];
    const float* b2     = (const float*)d_in[8];
    const float* saw    = (const float*)d_in[9];
    const float* sab    = (const float*)d_in[10];
    const float* alpha1 = (const float*)d_in[11];
    const float* g1     = (const float*)d_in[12];
    const float* be1    = (const float*)d_in[13];
    const float* rm1    = (const float*)d_in[14];
    const float* rv1    = (const float*)d_in[15];
    const float* alpha2 = (const float*)d_in[16];
    const float* g2     = (const float*)d_in[17];
    const float* be2    = (const float*)d_in[18];
    const float* rm2    = (const float*)d_in[19];
    const float* rv2    = (const float*)d_in[20];

    const int B = 256, Cc = 256, Np = 196, CM = 2048;
    const int M = B * Np; // 50176

    auto al = [](size_t s) { return (s + 255) & ~(size_t)255; };
    char* ws = (char*)d_ws;
    const size_t o_t0  = 0;
    const size_t o_t1  = o_t0 + al((size_t)M * Cc * 2);
    const size_t o_wq  = o_t1 + al((size_t)M * Cc * 2);
    const size_t o_wp  = o_wq + al((size_t)768 * Cc * 2);
    const size_t o_w1  = o_wp + al((size_t)Cc * Cc * 2);
    const size_t o_w2  = o_w1 + al((size_t)Cc * CM * 2);
    const size_t o_scr = o_w2 + al((size_t)CM * Cc * 2);
    const size_t S = (ws_size > o_scr) ? ws_size - o_scr : 0;

    u16* t0     = (u16*)(ws + o_t0);
    u16* t1b    = (u16*)(ws + o_t1);
    u16* WqkvT  = (u16*)(ws + o_wq);
    u16* WprojT = (u16*)(ws + o_wp);
    u16* W1T    = (u16*)(ws + o_w1);
    u16* W2T    = (u16*)(ws + o_w2);
    u16* scr    = (u16*)(ws + o_scr);
    u16* t2     = t0;            // alias: t0 dead after proj epilogue
    u16* obuf   = (u16*)d_out;   // bf16 scratch in f32 d_out; fully rewritten by final btrans
    float* out  = (float*)d_out;

    // chunk counts: row counts stay multiples of 128; nq | 256 (attn batches), nf | 392
    int nq = 1; while (nq < 8 && ((size_t)(M / nq) * 768 * 2) > S) nq *= 2;
    const int nf_opts[7] = {1, 2, 4, 8, 14, 28, 56};
    int nf = 56;
    for (int i = 0; i < 7; ++i) {
        if (((size_t)(M / nf_opts[i]) * CM * 2) <= S) { nf = nf_opts[i]; break; }
    }
    const int Mq = M / nq, Bq = B / nq;
    const int Mf = M / nf;

    dim3 tb(32, 8, 1);
    // x f32 [B][C][N] -> t0 bf16 [B][N][C]
    btrans_f2b<<<dim3((Np + 31) / 32, (Cc + 31) / 32, B), tb, 0, stream>>>(x, t0, Cc, Np);
    // weights f32 [K][N] -> bf16 [N][K]
    btrans_f2b<<<dim3(768 / 32, Cc / 32, 1), tb, 0, stream>>>(Wqkv,  WqkvT,  Cc, 768);
    btrans_f2b<<<dim3(Cc  / 32, Cc / 32, 1), tb, 0, stream>>>(Wproj, WprojT, Cc, Cc);
    btrans_f2b<<<dim3(CM  / 32, Cc / 32, 1), tb, 0, stream>>>(W1,    W1T,    Cc, CM);
    btrans_f2b<<<dim3(Cc  / 32, CM / 32, 1), tb, 0, stream>>>(W2,    W2T,    CM, Cc);

    // qkv + attention, chunked over batches
    for (int c = 0; c < nq; ++c) {
        gemm_bt<0><<<dim3(768 / 128, Mq / 128), 256, 0, stream>>>(
            t0 + (size_t)c * Mq * Cc, WqkvT, bqkv, scr, Mq, 768, Cc, 0,
            nullptr, nullptr, nullptr, nullptr, nullptr, nullptr, nullptr, nullptr);
        attn_kernel<<<dim3(Bq * 8), 256, 0, stream>>>(scr, obuf + (size_t)c * Mq * Cc);
    }

    // t1 = RepBN1(t0 + obuf @ Wproj + bproj)
    gemm_bt<1><<<dim3(Cc / 128, M / 128), 256, 0, stream>>>(
        obuf, WprojT, bproj, t1b, M, Cc, Cc, 0,
        t0, g1, be1, rm1, rv1, alpha1, nullptr, nullptr);

    // FFN, chunked over rows
    for (int c = 0; c < nf; ++c) {
        gemm_bt<2><<<dim3(CM / 128, Mf / 128), 256, 0, stream>>>(
            t1b + (size_t)c * Mf * Cc, W1T, b1, scr, Mf, CM, Cc, c * Mf,
            nullptr, nullptr, nullptr, nullptr, nullptr, nullptr, saw, sab);
        gemm_bt<1><<<dim3(Cc / 128, Mf / 128), 256, 0, stream>>>(
            scr, W2T, b2, t2 + (size_t)c * Mf * Cc, Mf, Cc, CM, 0,
            t1b + (size_t)c * Mf * Cc, g2, be2, rm2, rv2, alpha2, nullptr, nullptr);
    }

    // t2 bf16 [B][N][C] -> out f32 [B][C][N]
    btrans_b2f<<<dim3((Cc + 31) / 32, (Np + 31) / 32, B), tb, 0, stream>>>(t2, out, Np, Cc);
}

// Round 5
// 732.127 us; speedup vs baseline: 1.2931x; 1.2931x over previous
//
#include <hip/hip_runtime.h>

using u16 = unsigned short;

typedef __bf16 bf16x8 __attribute__((ext_vector_type(8)));
typedef u16    u16x8  __attribute__((ext_vector_type(8)));
typedef float  f32x4  __attribute__((ext_vector_type(4)));

__device__ __forceinline__ float b2f(u16 u) {
    union { unsigned int i; float f; } c; c.i = ((unsigned int)u) << 16; return c.f;
}
__device__ __forceinline__ u16 f2b(float f) {
    union { float f; unsigned int i; } c; c.f = f;
    unsigned int i = c.i;
    return (u16)((i + 0x7FFFu + ((i >> 16) & 1u)) >> 16);
}

#define AS1 __attribute__((address_space(1)))
#define AS3 __attribute__((address_space(3)))
__device__ __forceinline__ void glds16(const u16* g, u16* l) {
    __builtin_amdgcn_global_load_lds((const AS1 void*)(const void*)g,
                                     (AS3 void*)(void*)l, 16, 0, 0);
}

// ---------------------------------------------------------------------------
// Batched transpose + convert f32 -> bf16: in[b][R][C] f32 -> out[b][C][R] bf16
// ---------------------------------------------------------------------------
__global__ void btrans_f2b(const float* __restrict__ in, u16* __restrict__ out, int R, int C) {
    __shared__ u16 tile[32][33];
    const int c0 = blockIdx.x * 32, r0 = blockIdx.y * 32;
    const size_t base = (size_t)blockIdx.z * R * C;
    const int tx = threadIdx.x, ty = threadIdx.y;
    #pragma unroll
    for (int i = ty; i < 32; i += 8) {
        int r = r0 + i, c = c0 + tx;
        tile[i][tx] = (r < R && c < C) ? f2b(in[base + (size_t)r * C + c]) : (u16)0;
    }
    __syncthreads();
    #pragma unroll
    for (int i = ty; i < 32; i += 8) {
        int c = c0 + i, r = r0 + tx;
        if (c < C && r < R) out[base + (size_t)c * R + r] = tile[tx][i];
    }
}

// Batched transpose + convert bf16 -> f32: in[b][R][C] bf16 -> out[b][C][R] f32
__global__ void btrans_b2f(const u16* __restrict__ in, float* __restrict__ out, int R, int C) {
    __shared__ u16 tile[32][33];
    const int c0 = blockIdx.x * 32, r0 = blockIdx.y * 32;
    const size_t base = (size_t)blockIdx.z * R * C;
    const int tx = threadIdx.x, ty = threadIdx.y;
    #pragma unroll
    for (int i = ty; i < 32; i += 8) {
        int r = r0 + i, c = c0 + tx;
        tile[i][tx] = (r < R && c < C) ? in[base + (size_t)r * C + c] : (u16)0;
    }
    __syncthreads();
    #pragma unroll
    for (int i = ty; i < 32; i += 8) {
        int c = c0 + i, r = r0 + tx;
        if (c < C && r < R) out[base + (size_t)c * R + r] = b2f(tile[tx][i]);
    }
}

// ---------------------------------------------------------------------------
// m97-style GEMM: C[M,N] = epilogue(A[M,K] @ BT[N,K]^T + bias)   (A,BT,C bf16)
// 128x128 block tile, BK=32, 4 waves (2x2), each wave 4x4 tiles of 16x16x32.
// EPI: 0 = bias only (QKV)
//      1 = bias + residual(R0 bf16) + RepBN
//      2 = bias + SpatialSiLU (saw/sab indexed by (row0+row)/196)
// ---------------------------------------------------------------------------
template<int EPI>
__launch_bounds__(256)
__global__ void gemm_bt(const u16* __restrict__ A, const u16* __restrict__ BT,
                        const float* __restrict__ bias, u16* __restrict__ C,
                        int M, int N, int K, int row0,
                        const u16* __restrict__ R0,
                        const float* __restrict__ g, const float* __restrict__ be,
                        const float* __restrict__ rmv, const float* __restrict__ rvv,
                        const float* __restrict__ alpha,
                        const float* __restrict__ saw, const float* __restrict__ sab) {
    __shared__ __align__(16) u16 ALds[128 * 32];
    __shared__ __align__(16) u16 BLds[128 * 32];
    const int tid  = threadIdx.x;
    const int wave = tid >> 6, lane = tid & 63;
    const int wm = wave >> 1, wn = wave & 1;
    const int quad = lane >> 4, l16 = lane & 15;
    const int m0 = blockIdx.y * 128, n0 = blockIdx.x * 128;

    const int srow = lane >> 2;
    const int scol = (lane & 3) * 8;
    const u16* aG0 = A  + (size_t)(m0 + wave * 32 + srow) * K + scol;
    const u16* aG1 = aG0 + (size_t)16 * K;
    const u16* bG0 = BT + (size_t)(n0 + wave * 32 + srow) * K + scol;
    const u16* bG1 = bG0 + (size_t)16 * K;
    u16* aL0 = &ALds[(wave * 2    ) * 512];
    u16* aL1 = &ALds[(wave * 2 + 1) * 512];
    u16* bL0 = &BLds[(wave * 2    ) * 512];
    u16* bL1 = &BLds[(wave * 2 + 1) * 512];

    f32x4 acc[4][4] = {};

    for (int k0 = 0; k0 < K; k0 += 32) {
        glds16(aG0, aL0); glds16(aG1, aL1);
        glds16(bG0, bL0); glds16(bG1, bL1);
        aG0 += 32; aG1 += 32; bG0 += 32; bG1 += 32;
        __syncthreads();
        bf16x8 af[4], bfr[4];
        #pragma unroll
        for (int i = 0; i < 4; i++)
            af[i] = *(const bf16x8*)&ALds[(wm * 64 + i * 16 + l16) * 32 + quad * 8];
        #pragma unroll
        for (int j = 0; j < 4; j++)
            bfr[j] = *(const bf16x8*)&BLds[(wn * 64 + j * 16 + l16) * 32 + quad * 8];
        #pragma unroll
        for (int i = 0; i < 4; i++)
            #pragma unroll
            for (int j = 0; j < 4; j++)
                acc[i][j] = __builtin_amdgcn_mfma_f32_16x16x32_bf16(af[i], bfr[j], acc[i][j], 0, 0, 0);
        __syncthreads();
    }

    float alphav = 0.f;
    if (EPI == 1) alphav = alpha[0];

    #pragma unroll
    for (int i = 0; i < 4; i++) {
        const int rowb = m0 + wm * 64 + i * 16 + quad * 4;
        #pragma unroll
        for (int r = 0; r < 4; r++) {
            const int row = rowb + r;
            float swv = 0.f, sbv = 0.f;
            if (EPI == 2) { int bidx = (row0 + row) / 196; swv = saw[bidx]; sbv = sab[bidx]; }
            #pragma unroll
            for (int j = 0; j < 4; j++) {
                const int col = n0 + wn * 64 + j * 16 + l16;
                float v = acc[i][j][r] + bias[col];
                const size_t off = (size_t)row * N + col;
                if (EPI == 0) {
                    C[off] = f2b(v);
                } else if (EPI == 1) {
                    float x  = v + b2f(R0[off]);
                    float sc = g[col] * rsqrtf(rvv[col] + 1e-5f);
                    float t  = (x - rmv[col]) * sc + be[col] + alphav * x;
                    C[off]  = f2b(t);
                } else { // EPI == 2
                    float w   = swv * v + sbv;
                    float out = v / (1.f + __expf(-w * v));
                    C[off] = f2b(out);
                }
            }
        }
    }
}

// ---------------------------------------------------------------------------
// MFMA flash attention: one block per (local b, h), 4 waves.
// N=196 padded to 208 for S-cols (13 col-tiles), 224 for PV K-dim.
// K in LDS [224x32] (rows >=196 zero); V^T in LDS [32 x 232] (stride pad).
// Per 16-row tile (13 tiles over 4 waves): 13 QK mfma -> full-row softmax in
// regs (shuffle-reduce over 16 lanes) -> P via LDS (C-layout -> A-layout) ->
// 14 PV mfma -> scale by 1/rowsum -> store.
// qkv layout (bf16): row = b*196+n, col = s*256 + h*32 + d
// ---------------------------------------------------------------------------
__launch_bounds__(256)
__global__ void attn_kernel(const u16* __restrict__ qkv, u16* __restrict__ o) {
    __shared__ __align__(16) u16 Kb[224 * 32];     // K rows
    __shared__ __align__(16) u16 Vt[32 * 232];     // V transposed, stride 232
    __shared__ __align__(16) u16 Pl[4][16 * 232];  // per-wave P tile, stride 232
    const int tid  = threadIdx.x;
    const int wave = tid >> 6, lane = tid & 63;
    const int quad = lane >> 4, l16 = lane & 15;
    const int b = blockIdx.x >> 3, h = blockIdx.x & 7;
    const u16* qg = qkv + (size_t)b * 196 * 768 + h * 32;
    const float scale = 0.17677669529663687f; // 1/sqrt(32)

    // stage K (vectorized) and V^T (scalar scatter)
    for (int idx = tid; idx < 896; idx += 256) {          // 224 rows x 4 chunks of 8
        int row = idx >> 2, dp = (idx & 3) * 8;
        u16x8 kv = {};
        if (row < 196) kv = *(const u16x8*)&qg[(size_t)row * 768 + 256 + dp];
        *(u16x8*)&Kb[row * 32 + dp] = kv;
    }
    for (int idx = tid; idx < 224 * 32; idx += 256) {
        int row = idx >> 5, d = idx & 31;
        Vt[d * 232 + row] = (row < 196) ? qg[(size_t)row * 768 + 512 + d] : (u16)0;
    }
    // zero pad cols 208..231 of this wave's P tile (never written later)
    for (int c = lane; c < 16 * 24; c += 64) {
        int m = c / 24, cc = 208 + (c % 24);
        Pl[wave][m * 232 + cc] = 0;
    }
    __syncthreads();

    for (int t = wave; t < 13; t += 4) {
        const int m0 = t * 16;
        // Q A-frag straight from global: lane row = m0+l16, k = quad*8..+7
        bf16x8 aq = {};
        const int qrow = m0 + l16;
        if (qrow < 196) aq = *(const bf16x8*)&qg[(size_t)qrow * 768 + quad * 8];

        f32x4 s[13];
        #pragma unroll
        for (int ct = 0; ct < 13; ct++) {
            bf16x8 bk = *(const bf16x8*)&Kb[(ct * 16 + l16) * 32 + quad * 8];
            s[ct] = __builtin_amdgcn_mfma_f32_16x16x32_bf16(aq, bk, (f32x4){0.f, 0.f, 0.f, 0.f}, 0, 0, 0);
        }
        // mask cols 196..207 (tile 12, l16 >= 4)
        if (l16 >= 4) {
            #pragma unroll
            for (int r = 0; r < 4; r++) s[12][r] = -1e30f;
        }
        // row max (rows = quad*4+r), reduce over l16 lanes
        float mx[4] = {-1e30f, -1e30f, -1e30f, -1e30f};
        #pragma unroll
        for (int ct = 0; ct < 13; ct++)
            #pragma unroll
            for (int r = 0; r < 4; r++) mx[r] = fmaxf(mx[r], s[ct][r]);
        #pragma unroll
        for (int off = 1; off < 16; off <<= 1)
            #pragma unroll
            for (int r = 0; r < 4; r++) mx[r] = fmaxf(mx[r], __shfl_xor(mx[r], off, 64));
        // p = exp((s-mx)*scale), accumulate row sums, write P to LDS [row][col]
        float sum[4] = {0.f, 0.f, 0.f, 0.f};
        #pragma unroll
        for (int ct = 0; ct < 13; ct++) {
            #pragma unroll
            for (int r = 0; r < 4; r++) {
                float p = __expf((s[ct][r] - mx[r]) * scale);
                sum[r] += p;
                Pl[wave][(quad * 4 + r) * 232 + ct * 16 + l16] = f2b(p);
            }
        }
        #pragma unroll
        for (int off = 1; off < 16; off <<= 1)
            #pragma unroll
            for (int r = 0; r < 4; r++) sum[r] += __shfl_xor(sum[r], off, 64);
        float inv[4];
        #pragma unroll
        for (int r = 0; r < 4; r++) inv[r] = 1.f / sum[r];

        // O = P @ V : A-frag from Pl rows (m=l16), B-frag from Vt rows (n=l16)
        #pragma unroll
        for (int nt = 0; nt < 2; nt++) {
            f32x4 ao = {0.f, 0.f, 0.f, 0.f};
            #pragma unroll
            for (int kc = 0; kc < 7; kc++) {
                bf16x8 ap = *(const bf16x8*)&Pl[wave][l16 * 232 + kc * 32 + quad * 8];
                bf16x8 bv = *(const bf16x8*)&Vt[(nt * 16 + l16) * 232 + kc * 32 + quad * 8];
                ao = __builtin_amdgcn_mfma_f32_16x16x32_bf16(ap, bv, ao, 0, 0, 0);
            }
            #pragma unroll
            for (int r = 0; r < 4; r++) {
                const int gm = m0 + quad * 4 + r;
                if (gm < 196)
                    o[((size_t)b * 196 + gm) * 256 + h * 32 + nt * 16 + l16] = f2b(ao[r] * inv[r]);
            }
        }
    }
}

// ---------------------------------------------------------------------------
extern "C" void kernel_launch(void* const* d_in, const int* in_sizes, int n_in,
                              void* d_out, int out_size, void* d_ws, size_t ws_size,
                              hipStream_t stream) {
    // All inputs are float32 per the reference's setup_inputs().
    const float* x      = (const float*)d_in[0];
    const float* Wqkv   = (const float*)d_in[1];
    const float* bqkv   = (const float*)d_in[2];
    const float* Wproj  = (const float*)d_in[3];
    const float* bproj  = (const float*)d_in[4];
    const float* W1     = (const float*)d_in[5];
    const float* b1     = (const float*)d_in[6];
    const float* W2     = (const float*)d_in[7];
    const float* b2     = (const float*)d_in[8];
    const float* saw    = (const float*)d_in[9];
    const float* sab    = (const float*)d_in[10];
    const float* alpha1 = (const float*)d_in[11];
    const float* g1     = (const float*)d_in[12];
    const float* be1    = (const float*)d_in[13];
    const float* rm1    = (const float*)d_in[14];
    const float* rv1    = (const float*)d_in[15];
    const float* alpha2 = (const float*)d_in[16];
    const float* g2     = (const float*)d_in[17];
    const float* be2    = (const float*)d_in[18];
    const float* rm2    = (const float*)d_in[19];
    const float* rv2    = (const float*)d_in[20];

    const int B = 256, Cc = 256, Np = 196, CM = 2048;
    const int M = B * Np; // 50176

    auto al = [](size_t s) { return (s + 255) & ~(size_t)255; };
    char* ws = (char*)d_ws;
    const size_t o_t0  = 0;
    const size_t o_t1  = o_t0 + al((size_t)M * Cc * 2);
    const size_t o_wq  = o_t1 + al((size_t)M * Cc * 2);
    const size_t o_wp  = o_wq + al((size_t)768 * Cc * 2);
    const size_t o_w1  = o_wp + al((size_t)Cc * Cc * 2);
    const size_t o_w2  = o_w1 + al((size_t)Cc * CM * 2);
    const size_t o_scr = o_w2 + al((size_t)CM * Cc * 2);
    const size_t S = (ws_size > o_scr) ? ws_size - o_scr : 0;

    u16* t0     = (u16*)(ws + o_t0);
    u16* t1b    = (u16*)(ws + o_t1);
    u16* WqkvT  = (u16*)(ws + o_wq);
    u16* WprojT = (u16*)(ws + o_wp);
    u16* W1T    = (u16*)(ws + o_w1);
    u16* W2T    = (u16*)(ws + o_w2);
    u16* scr    = (u16*)(ws + o_scr);
    u16* t2     = t0;            // alias: t0 dead after proj epilogue
    u16* obuf   = (u16*)d_out;   // bf16 scratch in f32 d_out; fully rewritten by final btrans
    float* out  = (float*)d_out;

    // chunk counts: row counts stay multiples of 128; nq | 256 (attn batches), nf | 392
    int nq = 1; while (nq < 8 && ((size_t)(M / nq) * 768 * 2) > S) nq *= 2;
    const int nf_opts[7] = {1, 2, 4, 8, 14, 28, 56};
    int nf = 56;
    for (int i = 0; i < 7; ++i) {
        if (((size_t)(M / nf_opts[i]) * CM * 2) <= S) { nf = nf_opts[i]; break; }
    }
    const int Mq = M / nq, Bq = B / nq;
    const int Mf = M / nf;

    dim3 tb(32, 8, 1);
    // x f32 [B][C][N] -> t0 bf16 [B][N][C]
    btrans_f2b<<<dim3((Np + 31) / 32, (Cc + 31) / 32, B), tb, 0, stream>>>(x, t0, Cc, Np);
    // weights f32 [K][N] -> bf16 [N][K]
    btrans_f2b<<<dim3(768 / 32, Cc / 32, 1), tb, 0, stream>>>(Wqkv,  WqkvT,  Cc, 768);
    btrans_f2b<<<dim3(Cc  / 32, Cc / 32, 1), tb, 0, stream>>>(Wproj, WprojT, Cc, Cc);
    btrans_f2b<<<dim3(CM  / 32, Cc / 32, 1), tb, 0, stream>>>(W1,    W1T,    Cc, CM);
    btrans_f2b<<<dim3(Cc  / 32, CM / 32, 1), tb, 0, stream>>>(W2,    W2T,    CM, Cc);

    // qkv + attention, chunked over batches
    for (int c = 0; c < nq; ++c) {
        gemm_bt<0><<<dim3(768 / 128, Mq / 128), 256, 0, stream>>>(
            t0 + (size_t)c * Mq * Cc, WqkvT, bqkv, scr, Mq, 768, Cc, 0,
            nullptr, nullptr, nullptr, nullptr, nullptr, nullptr, nullptr, nullptr);
        attn_kernel<<<dim3(Bq * 8), 256, 0, stream>>>(scr, obuf + (size_t)c * Mq * Cc);
    }

    // t1 = RepBN1(t0 + obuf @ Wproj + bproj)
    gemm_bt<1><<<dim3(Cc / 128, M / 128), 256, 0, stream>>>(
        obuf, WprojT, bproj, t1b, M, Cc, Cc, 0,
        t0, g1, be1, rm1, rv1, alpha1, nullptr, nullptr);

    // FFN, chunked over rows
    for (int c = 0; c < nf; ++c) {
        gemm_bt<2><<<dim3(CM / 128, Mf / 128), 256, 0, stream>>>(
            t1b + (size_t)c * Mf * Cc, W1T, b1, scr, Mf, CM, Cc, c * Mf,
            nullptr, nullptr, nullptr, nullptr, nullptr, nullptr, saw, sab);
        gemm_bt<1><<<dim3(Cc / 128, Mf / 128), 256, 0, stream>>>(
            scr, W2T, b2, t2 + (size_t)c * Mf * Cc, Mf, Cc, CM, 0,
            t1b + (size_t)c * Mf * Cc, g2, be2, rm2, rv2, alpha2, nullptr, nullptr);
    }

    // t2 bf16 [B][N][C] -> out f32 [B][C][N]
    btrans_b2f<<<dim3((Cc + 31) / 32, (Np + 31) / 32, B), tb, 0, stream>>>(t2, out, Np, Cc);
}

// Round 6
// 699.718 us; speedup vs baseline: 1.3530x; 1.0463x over previous
//
#include <hip/hip_runtime.h>

using u16 = unsigned short;

typedef __bf16 bf16x8 __attribute__((ext_vector_type(8)));
typedef u16    u16x8  __attribute__((ext_vector_type(8)));
typedef float  f32x4  __attribute__((ext_vector_type(4)));

__device__ __forceinline__ float b2f(u16 u) {
    union { unsigned int i; float f; } c; c.i = ((unsigned int)u) << 16; return c.f;
}
__device__ __forceinline__ u16 f2b(float f) {
    union { float f; unsigned int i; } c; c.f = f;
    unsigned int i = c.i;
    return (u16)((i + 0x7FFFu + ((i >> 16) & 1u)) >> 16);
}

#define AS1 __attribute__((address_space(1)))
#define AS3 __attribute__((address_space(3)))
__device__ __forceinline__ void glds16(const u16* g, u16* l) {
    __builtin_amdgcn_global_load_lds((const AS1 void*)(const void*)g,
                                     (AS3 void*)(void*)l, 16, 0, 0);
}

// ---------------------------------------------------------------------------
// Batched transpose + convert f32 -> bf16: in[b][R][C] f32 -> out[b][C][R] bf16
// ---------------------------------------------------------------------------
__global__ void btrans_f2b(const float* __restrict__ in, u16* __restrict__ out, int R, int C) {
    __shared__ u16 tile[32][33];
    const int c0 = blockIdx.x * 32, r0 = blockIdx.y * 32;
    const size_t base = (size_t)blockIdx.z * R * C;
    const int tx = threadIdx.x, ty = threadIdx.y;
    #pragma unroll
    for (int i = ty; i < 32; i += 8) {
        int r = r0 + i, c = c0 + tx;
        tile[i][tx] = (r < R && c < C) ? f2b(in[base + (size_t)r * C + c]) : (u16)0;
    }
    __syncthreads();
    #pragma unroll
    for (int i = ty; i < 32; i += 8) {
        int c = c0 + i, r = r0 + tx;
        if (c < C && r < R) out[base + (size_t)c * R + r] = tile[tx][i];
    }
}

// Batched transpose + convert bf16 -> f32: in[b][R][C] bf16 -> out[b][C][R] f32
__global__ void btrans_b2f(const u16* __restrict__ in, float* __restrict__ out, int R, int C) {
    __shared__ u16 tile[32][33];
    const int c0 = blockIdx.x * 32, r0 = blockIdx.y * 32;
    const size_t base = (size_t)blockIdx.z * R * C;
    const int tx = threadIdx.x, ty = threadIdx.y;
    #pragma unroll
    for (int i = ty; i < 32; i += 8) {
        int r = r0 + i, c = c0 + tx;
        tile[i][tx] = (r < R && c < C) ? in[base + (size_t)r * C + c] : (u16)0;
    }
    __syncthreads();
    #pragma unroll
    for (int i = ty; i < 32; i += 8) {
        int c = c0 + i, r = r0 + tx;
        if (c < C && r < R) out[base + (size_t)c * R + r] = b2f(tile[tx][i]);
    }
}

// ---------------------------------------------------------------------------
// GEMM: C[M,N] = epilogue(A[M,K] @ BT[N,K]^T + bias)   (A,BT,C bf16)
// 128x128 block tile, BK=64 (two 32-k panels), 4 waves (2x2), 4x4 acc tiles
// of 16x16x32. LDS k-chunks XOR-swizzled: LDS[row][c] holds global chunk
// c ^ ((row>>1)&3)  -> fragment ds_read_b128 is 2-way-bank (free).
// EPI: 0 = bias only; 1 = bias+residual+RepBN; 2 = bias+SpatialSiLU
// ---------------------------------------------------------------------------
template<int EPI>
__launch_bounds__(256)
__global__ void gemm_bt(const u16* __restrict__ A, const u16* __restrict__ BT,
                        const float* __restrict__ bias, u16* __restrict__ C,
                        int M, int N, int K, int row0,
                        const u16* __restrict__ R0,
                        const float* __restrict__ g, const float* __restrict__ be,
                        const float* __restrict__ rmv, const float* __restrict__ rvv,
                        const float* __restrict__ alpha,
                        const float* __restrict__ saw, const float* __restrict__ sab) {
    __shared__ __align__(16) u16 ALds[2][128 * 32];
    __shared__ __align__(16) u16 BLds[2][128 * 32];
    const int tid  = threadIdx.x;
    const int wave = tid >> 6, lane = tid & 63;
    const int wm = wave >> 1, wn = wave & 1;
    const int quad = lane >> 4, l16 = lane & 15;
    const int m0 = blockIdx.y * 128, n0 = blockIdx.x * 128;

    // staging: wave stages rows [wave*32, wave*32+32) for both k-panels.
    // lane -> row = wave*32 + (lane>>2), global k-chunk swizzled by row.
    const int srow = lane >> 2;                                   // 0..15
    const int scol = (((lane & 3) ^ ((srow >> 1) & 3)) * 8);      // swizzled source chunk
    const size_t aoff0 = (size_t)(m0 + wave * 32 + srow) * K + scol;
    const size_t aoff1 = aoff0 + (size_t)16 * K;
    const size_t boff0 = (size_t)(n0 + wave * 32 + srow) * K + scol;
    const size_t boff1 = boff0 + (size_t)16 * K;
    u16* aL0 = &ALds[0][(wave * 2    ) * 512];
    u16* aL1 = &ALds[0][(wave * 2 + 1) * 512];
    u16* bL0 = &BLds[0][(wave * 2    ) * 512];
    u16* bL1 = &BLds[0][(wave * 2 + 1) * 512];
    const int panel = 128 * 32;   // u16 elements per panel

    // fragment read column (undo swizzle): global chunk = quad
    const int cfrag = (quad ^ ((l16 >> 1) & 3)) * 8;

    f32x4 acc[4][4] = {};

    for (int k0 = 0; k0 < K; k0 += 64) {
        // panel 0 (k0..k0+31) and panel 1 (k0+32..k0+63)
        glds16(A  + aoff0 + k0,      aL0);
        glds16(A  + aoff1 + k0,      aL1);
        glds16(BT + boff0 + k0,      bL0);
        glds16(BT + boff1 + k0,      bL1);
        glds16(A  + aoff0 + k0 + 32, aL0 + panel);
        glds16(A  + aoff1 + k0 + 32, aL1 + panel);
        glds16(BT + boff0 + k0 + 32, bL0 + panel);
        glds16(BT + boff1 + k0 + 32, bL1 + panel);
        __syncthreads();
        bf16x8 af[2][4], bfr[2][4];
        #pragma unroll
        for (int p = 0; p < 2; p++) {
            #pragma unroll
            for (int i = 0; i < 4; i++)
                af[p][i] = *(const bf16x8*)&ALds[p][(wm * 64 + i * 16 + l16) * 32 + cfrag];
            #pragma unroll
            for (int j = 0; j < 4; j++)
                bfr[p][j] = *(const bf16x8*)&BLds[p][(wn * 64 + j * 16 + l16) * 32 + cfrag];
        }
        #pragma unroll
        for (int i = 0; i < 4; i++)
            #pragma unroll
            for (int j = 0; j < 4; j++) {
                acc[i][j] = __builtin_amdgcn_mfma_f32_16x16x32_bf16(af[0][i], bfr[0][j], acc[i][j], 0, 0, 0);
                acc[i][j] = __builtin_amdgcn_mfma_f32_16x16x32_bf16(af[1][i], bfr[1][j], acc[i][j], 0, 0, 0);
            }
        __syncthreads();
    }

    float alphav = 0.f;
    if (EPI == 1) alphav = alpha[0];

    #pragma unroll
    for (int i = 0; i < 4; i++) {
        const int rowb = m0 + wm * 64 + i * 16 + quad * 4;
        #pragma unroll
        for (int r = 0; r < 4; r++) {
            const int row = rowb + r;
            float swv = 0.f, sbv = 0.f;
            if (EPI == 2) { int bidx = (row0 + row) / 196; swv = saw[bidx]; sbv = sab[bidx]; }
            #pragma unroll
            for (int j = 0; j < 4; j++) {
                const int col = n0 + wn * 64 + j * 16 + l16;
                float v = acc[i][j][r] + bias[col];
                const size_t off = (size_t)row * N + col;
                if (EPI == 0) {
                    C[off] = f2b(v);
                } else if (EPI == 1) {
                    float x  = v + b2f(R0[off]);
                    float sc = g[col] * rsqrtf(rvv[col] + 1e-5f);
                    float t  = (x - rmv[col]) * sc + be[col] + alphav * x;
                    C[off]  = f2b(t);
                } else { // EPI == 2
                    float w   = swv * v + sbv;
                    float out = v / (1.f + __expf(-w * v));
                    C[off] = f2b(out);
                }
            }
        }
    }
}

// ---------------------------------------------------------------------------
// MFMA flash attention: one block per (local b, h), 4 waves. (unchanged R5)
// ---------------------------------------------------------------------------
__launch_bounds__(256)
__global__ void attn_kernel(const u16* __restrict__ qkv, u16* __restrict__ o) {
    __shared__ __align__(16) u16 Kb[224 * 32];     // K rows
    __shared__ __align__(16) u16 Vt[32 * 232];     // V transposed, stride 232
    __shared__ __align__(16) u16 Pl[4][16 * 232];  // per-wave P tile, stride 232
    const int tid  = threadIdx.x;
    const int wave = tid >> 6, lane = tid & 63;
    const int quad = lane >> 4, l16 = lane & 15;
    const int b = blockIdx.x >> 3, h = blockIdx.x & 7;
    const u16* qg = qkv + (size_t)b * 196 * 768 + h * 32;
    const float scale = 0.17677669529663687f; // 1/sqrt(32)

    for (int idx = tid; idx < 896; idx += 256) {          // 224 rows x 4 chunks of 8
        int row = idx >> 2, dp = (idx & 3) * 8;
        u16x8 kv = {};
        if (row < 196) kv = *(const u16x8*)&qg[(size_t)row * 768 + 256 + dp];
        *(u16x8*)&Kb[row * 32 + dp] = kv;
    }
    for (int idx = tid; idx < 224 * 32; idx += 256) {
        int row = idx >> 5, d = idx & 31;
        Vt[d * 232 + row] = (row < 196) ? qg[(size_t)row * 768 + 512 + d] : (u16)0;
    }
    for (int c = lane; c < 16 * 24; c += 64) {
        int m = c / 24, cc = 208 + (c % 24);
        Pl[wave][m * 232 + cc] = 0;
    }
    __syncthreads();

    for (int t = wave; t < 13; t += 4) {
        const int m0 = t * 16;
        bf16x8 aq = {};
        const int qrow = m0 + l16;
        if (qrow < 196) aq = *(const bf16x8*)&qg[(size_t)qrow * 768 + quad * 8];

        f32x4 s[13];
        #pragma unroll
        for (int ct = 0; ct < 13; ct++) {
            bf16x8 bk = *(const bf16x8*)&Kb[(ct * 16 + l16) * 32 + quad * 8];
            s[ct] = __builtin_amdgcn_mfma_f32_16x16x32_bf16(aq, bk, (f32x4){0.f, 0.f, 0.f, 0.f}, 0, 0, 0);
        }
        if (l16 >= 4) {
            #pragma unroll
            for (int r = 0; r < 4; r++) s[12][r] = -1e30f;
        }
        float mx[4] = {-1e30f, -1e30f, -1e30f, -1e30f};
        #pragma unroll
        for (int ct = 0; ct < 13; ct++)
            #pragma unroll
            for (int r = 0; r < 4; r++) mx[r] = fmaxf(mx[r], s[ct][r]);
        #pragma unroll
        for (int off = 1; off < 16; off <<= 1)
            #pragma unroll
            for (int r = 0; r < 4; r++) mx[r] = fmaxf(mx[r], __shfl_xor(mx[r], off, 64));
        float sum[4] = {0.f, 0.f, 0.f, 0.f};
        #pragma unroll
        for (int ct = 0; ct < 13; ct++) {
            #pragma unroll
            for (int r = 0; r < 4; r++) {
                float p = __expf((s[ct][r] - mx[r]) * scale);
                sum[r] += p;
                Pl[wave][(quad * 4 + r) * 232 + ct * 16 + l16] = f2b(p);
            }
        }
        #pragma unroll
        for (int off = 1; off < 16; off <<= 1)
            #pragma unroll
            for (int r = 0; r < 4; r++) sum[r] += __shfl_xor(sum[r], off, 64);
        float inv[4];
        #pragma unroll
        for (int r = 0; r < 4; r++) inv[r] = 1.f / sum[r];

        #pragma unroll
        for (int nt = 0; nt < 2; nt++) {
            f32x4 ao = {0.f, 0.f, 0.f, 0.f};
            #pragma unroll
            for (int kc = 0; kc < 7; kc++) {
                bf16x8 ap = *(const bf16x8*)&Pl[wave][l16 * 232 + kc * 32 + quad * 8];
                bf16x8 bv = *(const bf16x8*)&Vt[(nt * 16 + l16) * 232 + kc * 32 + quad * 8];
                ao = __builtin_amdgcn_mfma_f32_16x16x32_bf16(ap, bv, ao, 0, 0, 0);
            }
            #pragma unroll
            for (int r = 0; r < 4; r++) {
                const int gm = m0 + quad * 4 + r;
                if (gm < 196)
                    o[((size_t)b * 196 + gm) * 256 + h * 32 + nt * 16 + l16] = f2b(ao[r] * inv[r]);
            }
        }
    }
}

// ---------------------------------------------------------------------------
extern "C" void kernel_launch(void* const* d_in, const int* in_sizes, int n_in,
                              void* d_out, int out_size, void* d_ws, size_t ws_size,
                              hipStream_t stream) {
    // All inputs are float32 per the reference's setup_inputs().
    const float* x      = (const float*)d_in[0];
    const float* Wqkv   = (const float*)d_in[1];
    const float* bqkv   = (const float*)d_in[2];
    const float* Wproj  = (const float*)d_in[3];
    const float* bproj  = (const float*)d_in[4];
    const float* W1     = (const float*)d_in[5];
    const float* b1     = (const float*)d_in[6];
    const float* W2     = (const float*)d_in[7];
    const float* b2     = (const float*)d_in[8];
    const float* saw    = (const float*)d_in[9];
    const float* sab    = (const float*)d_in[10];
    const float* alpha1 = (const float*)d_in[11];
    const float* g1     = (const float*)d_in[12];
    const float* be1    = (const float*)d_in[13];
    const float* rm1    = (const float*)d_in[14];
    const float* rv1    = (const float*)d_in[15];
    const float* alpha2 = (const float*)d_in[16];
    const float* g2     = (const float*)d_in[17];
    const float* be2    = (const float*)d_in[18];
    const float* rm2    = (const float*)d_in[19];
    const float* rv2    = (const float*)d_in[20];

    const int B = 256, Cc = 256, Np = 196, CM = 2048;
    const int M = B * Np; // 50176

    auto al = [](size_t s) { return (s + 255) & ~(size_t)255; };
    char* ws = (char*)d_ws;
    const size_t o_t0  = 0;
    const size_t o_t1  = o_t0 + al((size_t)M * Cc * 2);
    const size_t o_wq  = o_t1 + al((size_t)M * Cc * 2);
    const size_t o_wp  = o_wq + al((size_t)768 * Cc * 2);
    const size_t o_w1  = o_wp + al((size_t)Cc * Cc * 2);
    const size_t o_w2  = o_w1 + al((size_t)Cc * CM * 2);
    const size_t o_scr = o_w2 + al((size_t)CM * Cc * 2);
    const size_t S = (ws_size > o_scr) ? ws_size - o_scr : 0;

    u16* t0     = (u16*)(ws + o_t0);
    u16* t1b    = (u16*)(ws + o_t1);
    u16* WqkvT  = (u16*)(ws + o_wq);
    u16* WprojT = (u16*)(ws + o_wp);
    u16* W1T    = (u16*)(ws + o_w1);
    u16* W2T    = (u16*)(ws + o_w2);
    u16* scr    = (u16*)(ws + o_scr);
    u16* t2     = t0;            // alias: t0 dead after proj epilogue
    u16* obuf   = (u16*)d_out;   // bf16 scratch in f32 d_out; fully rewritten by final btrans
    float* out  = (float*)d_out;

    // chunk counts: row counts stay multiples of 128; nq | 256 (attn batches), nf | 392
    int nq = 1; while (nq < 8 && ((size_t)(M / nq) * 768 * 2) > S) nq *= 2;
    const int nf_opts[7] = {1, 2, 4, 8, 14, 28, 56};
    int nf = 56;
    for (int i = 0; i < 7; ++i) {
        if (((size_t)(M / nf_opts[i]) * CM * 2) <= S) { nf = nf_opts[i]; break; }
    }
    const int Mq = M / nq, Bq = B / nq;
    const int Mf = M / nf;

    dim3 tb(32, 8, 1);
    // x f32 [B][C][N] -> t0 bf16 [B][N][C]
    btrans_f2b<<<dim3((Np + 31) / 32, (Cc + 31) / 32, B), tb, 0, stream>>>(x, t0, Cc, Np);
    // weights f32 [K][N] -> bf16 [N][K]
    btrans_f2b<<<dim3(768 / 32, Cc / 32, 1), tb, 0, stream>>>(Wqkv,  WqkvT,  Cc, 768);
    btrans_f2b<<<dim3(Cc  / 32, Cc / 32, 1), tb, 0, stream>>>(Wproj, WprojT, Cc, Cc);
    btrans_f2b<<<dim3(CM  / 32, Cc / 32, 1), tb, 0, stream>>>(W1,    W1T,    Cc, CM);
    btrans_f2b<<<dim3(Cc  / 32, CM / 32, 1), tb, 0, stream>>>(W2,    W2T,    CM, Cc);

    // qkv + attention, chunked over batches
    for (int c = 0; c < nq; ++c) {
        gemm_bt<0><<<dim3(768 / 128, Mq / 128), 256, 0, stream>>>(
            t0 + (size_t)c * Mq * Cc, WqkvT, bqkv, scr, Mq, 768, Cc, 0,
            nullptr, nullptr, nullptr, nullptr, nullptr, nullptr, nullptr, nullptr);
        attn_kernel<<<dim3(Bq * 8), 256, 0, stream>>>(scr, obuf + (size_t)c * Mq * Cc);
    }

    // t1 = RepBN1(t0 + obuf @ Wproj + bproj)
    gemm_bt<1><<<dim3(Cc / 128, M / 128), 256, 0, stream>>>(
        obuf, WprojT, bproj, t1b, M, Cc, Cc, 0,
        t0, g1, be1, rm1, rv1, alpha1, nullptr, nullptr);

    // FFN, chunked over rows
    for (int c = 0; c < nf; ++c) {
        gemm_bt<2><<<dim3(CM / 128, Mf / 128), 256, 0, stream>>>(
            t1b + (size_t)c * Mf * Cc, W1T, b1, scr, Mf, CM, Cc, c * Mf,
            nullptr, nullptr, nullptr, nullptr, nullptr, nullptr, saw, sab);
        gemm_bt<1><<<dim3(Cc / 128, Mf / 128), 256, 0, stream>>>(
            scr, W2T, b2, t2 + (size_t)c * Mf * Cc, Mf, Cc, CM, 0,
            t1b + (size_t)c * Mf * Cc, g2, be2, rm2, rv2, alpha2, nullptr, nullptr);
    }

    // t2 bf16 [B][N][C] -> out f32 [B][C][N]
    btrans_b2f<<<dim3((Cc + 31) / 32, (Np + 31) / 32, B), tb, 0, stream>>>(t2, out, Np, Cc);
}

// Round 7
// 655.230 us; speedup vs baseline: 1.4448x; 1.0679x over previous
//
#include <hip/hip_runtime.h>

using u16 = unsigned short;

typedef __bf16 bf16x8 __attribute__((ext_vector_type(8)));
typedef u16    u16x8  __attribute__((ext_vector_type(8)));
typedef float  f32x4  __attribute__((ext_vector_type(4)));

__device__ __forceinline__ float b2f(u16 u) {
    union { unsigned int i; float f; } c; c.i = ((unsigned int)u) << 16; return c.f;
}
__device__ __forceinline__ u16 f2b(float f) {
    union { float f; unsigned int i; } c; c.f = f;
    unsigned int i = c.i;
    return (u16)((i + 0x7FFFu + ((i >> 16) & 1u)) >> 16);
}

#define AS1 __attribute__((address_space(1)))
#define AS3 __attribute__((address_space(3)))
__device__ __forceinline__ void glds16(const u16* g, u16* l) {
    __builtin_amdgcn_global_load_lds((const AS1 void*)(const void*)g,
                                     (AS3 void*)(void*)l, 16, 0, 0);
}

// ---------------------------------------------------------------------------
// Batched transpose + convert f32 -> bf16: in[b][R][C] f32 -> out[b][C][R] bf16
// ---------------------------------------------------------------------------
__global__ void btrans_f2b(const float* __restrict__ in, u16* __restrict__ out, int R, int C) {
    __shared__ u16 tile[32][33];
    const int c0 = blockIdx.x * 32, r0 = blockIdx.y * 32;
    const size_t base = (size_t)blockIdx.z * R * C;
    const int tx = threadIdx.x, ty = threadIdx.y;
    #pragma unroll
    for (int i = ty; i < 32; i += 8) {
        int r = r0 + i, c = c0 + tx;
        tile[i][tx] = (r < R && c < C) ? f2b(in[base + (size_t)r * C + c]) : (u16)0;
    }
    __syncthreads();
    #pragma unroll
    for (int i = ty; i < 32; i += 8) {
        int c = c0 + i, r = r0 + tx;
        if (c < C && r < R) out[base + (size_t)c * R + r] = tile[tx][i];
    }
}

// Batched transpose + convert bf16 -> f32: in[b][R][C] bf16 -> out[b][C][R] f32
__global__ void btrans_b2f(const u16* __restrict__ in, float* __restrict__ out, int R, int C) {
    __shared__ u16 tile[32][33];
    const int c0 = blockIdx.x * 32, r0 = blockIdx.y * 32;
    const size_t base = (size_t)blockIdx.z * R * C;
    const int tx = threadIdx.x, ty = threadIdx.y;
    #pragma unroll
    for (int i = ty; i < 32; i += 8) {
        int r = r0 + i, c = c0 + tx;
        tile[i][tx] = (r < R && c < C) ? in[base + (size_t)r * C + c] : (u16)0;
    }
    __syncthreads();
    #pragma unroll
    for (int i = ty; i < 32; i += 8) {
        int c = c0 + i, r = r0 + tx;
        if (c < C && r < R) out[base + (size_t)c * R + r] = b2f(tile[tx][i]);
    }
}

// ---------------------------------------------------------------------------
// GEMM: C[M,N] = epilogue(A[M,K] @ BT[N,K]^T + bias)   (A,BT,C bf16)
// 128x128 block tile, BK=32, 4 waves (2x2), 4x4 acc tiles of 16x16x32.
// Single-barrier double-buffered K-loop: barrier drains loads issued one full
// iteration earlier (latency absorbed by compute), then prefetch k+1, then
// compute k. LDS k-chunks XOR-swizzled (conflict-free ds_read_b128).
// EPI: 0 = bias only; 1 = bias+residual+RepBN; 2 = bias+SpatialSiLU
// ---------------------------------------------------------------------------
template<int EPI>
__launch_bounds__(256)
__global__ void gemm_bt(const u16* __restrict__ A, const u16* __restrict__ BT,
                        const float* __restrict__ bias, u16* __restrict__ C,
                        int M, int N, int K, int row0,
                        const u16* __restrict__ R0,
                        const float* __restrict__ g, const float* __restrict__ be,
                        const float* __restrict__ rmv, const float* __restrict__ rvv,
                        const float* __restrict__ alpha,
                        const float* __restrict__ saw, const float* __restrict__ sab) {
    __shared__ __align__(16) u16 ALds[2][128 * 32];
    __shared__ __align__(16) u16 BLds[2][128 * 32];
    const int tid  = threadIdx.x;
    const int wave = tid >> 6, lane = tid & 63;
    const int wm = wave >> 1, wn = wave & 1;
    const int quad = lane >> 4, l16 = lane & 15;
    const int m0 = blockIdx.y * 128, n0 = blockIdx.x * 128;

    // staging: wave stages rows [wave*32, +32). lane -> row = wave*32+(lane>>2),
    // source k-chunk swizzled by row so LDS[row][c] holds global chunk c^((row>>1)&3).
    const int srow = lane >> 2;                                   // 0..15
    const int scol = (((lane & 3) ^ ((srow >> 1) & 3)) * 8);      // swizzled source chunk
    const size_t aoff0 = (size_t)(m0 + wave * 32 + srow) * K + scol;
    const size_t aoff1 = aoff0 + (size_t)16 * K;
    const size_t boff0 = (size_t)(n0 + wave * 32 + srow) * K + scol;
    const size_t boff1 = boff0 + (size_t)16 * K;
    u16* aD0[2] = { &ALds[0][(wave * 2    ) * 512], &ALds[1][(wave * 2    ) * 512] };
    u16* aD1[2] = { &ALds[0][(wave * 2 + 1) * 512], &ALds[1][(wave * 2 + 1) * 512] };
    u16* bD0[2] = { &BLds[0][(wave * 2    ) * 512], &BLds[1][(wave * 2    ) * 512] };
    u16* bD1[2] = { &BLds[0][(wave * 2 + 1) * 512], &BLds[1][(wave * 2 + 1) * 512] };

    // fragment read column (undo swizzle): global chunk = quad
    const int cfrag = (quad ^ ((l16 >> 1) & 3)) * 8;

    f32x4 acc[4][4] = {};
    const int niter = K >> 5;

    // prologue: issue tile 0 into buffer 0
    glds16(A  + aoff0, aD0[0]);
    glds16(A  + aoff1, aD1[0]);
    glds16(BT + boff0, bD0[0]);
    glds16(BT + boff1, bD1[0]);

    for (int kt = 0; kt < niter; kt++) {
        const int cur = kt & 1, nxt = cur ^ 1;
        __syncthreads();  // drains vmcnt(0): buf[cur] ready; buf[nxt] readers done
        if (kt + 1 < niter) {
            const size_t kn = (size_t)(kt + 1) << 5;
            glds16(A  + aoff0 + kn, aD0[nxt]);
            glds16(A  + aoff1 + kn, aD1[nxt]);
            glds16(BT + boff0 + kn, bD0[nxt]);
            glds16(BT + boff1 + kn, bD1[nxt]);
        }
        bf16x8 af[4], bfr[4];
        #pragma unroll
        for (int i = 0; i < 4; i++)
            af[i] = *(const bf16x8*)&ALds[cur][(wm * 64 + i * 16 + l16) * 32 + cfrag];
        #pragma unroll
        for (int j = 0; j < 4; j++)
            bfr[j] = *(const bf16x8*)&BLds[cur][(wn * 64 + j * 16 + l16) * 32 + cfrag];
        #pragma unroll
        for (int i = 0; i < 4; i++)
            #pragma unroll
            for (int j = 0; j < 4; j++)
                acc[i][j] = __builtin_amdgcn_mfma_f32_16x16x32_bf16(af[i], bfr[j], acc[i][j], 0, 0, 0);
    }

    float alphav = 0.f;
    if (EPI == 1) alphav = alpha[0];

    #pragma unroll
    for (int i = 0; i < 4; i++) {
        const int rowb = m0 + wm * 64 + i * 16 + quad * 4;
        #pragma unroll
        for (int r = 0; r < 4; r++) {
            const int row = rowb + r;
            float swv = 0.f, sbv = 0.f;
            if (EPI == 2) { int bidx = (row0 + row) / 196; swv = saw[bidx]; sbv = sab[bidx]; }
            #pragma unroll
            for (int j = 0; j < 4; j++) {
                const int col = n0 + wn * 64 + j * 16 + l16;
                float v = acc[i][j][r] + bias[col];
                const size_t off = (size_t)row * N + col;
                if (EPI == 0) {
                    C[off] = f2b(v);
                } else if (EPI == 1) {
                    float x  = v + b2f(R0[off]);
                    float sc = g[col] * rsqrtf(rvv[col] + 1e-5f);
                    float t  = (x - rmv[col]) * sc + be[col] + alphav * x;
                    C[off]  = f2b(t);
                } else { // EPI == 2
                    float w   = swv * v + sbv;
                    float out = v / (1.f + __expf(-w * v));
                    C[off] = f2b(out);
                }
            }
        }
    }
}

// ---------------------------------------------------------------------------
// MFMA flash attention: one block per (local b, h), 4 waves. (unchanged R5)
// ---------------------------------------------------------------------------
__launch_bounds__(256)
__global__ void attn_kernel(const u16* __restrict__ qkv, u16* __restrict__ o) {
    __shared__ __align__(16) u16 Kb[224 * 32];     // K rows
    __shared__ __align__(16) u16 Vt[32 * 232];     // V transposed, stride 232
    __shared__ __align__(16) u16 Pl[4][16 * 232];  // per-wave P tile, stride 232
    const int tid  = threadIdx.x;
    const int wave = tid >> 6, lane = tid & 63;
    const int quad = lane >> 4, l16 = lane & 15;
    const int b = blockIdx.x >> 3, h = blockIdx.x & 7;
    const u16* qg = qkv + (size_t)b * 196 * 768 + h * 32;
    const float scale = 0.17677669529663687f; // 1/sqrt(32)

    for (int idx = tid; idx < 896; idx += 256) {          // 224 rows x 4 chunks of 8
        int row = idx >> 2, dp = (idx & 3) * 8;
        u16x8 kv = {};
        if (row < 196) kv = *(const u16x8*)&qg[(size_t)row * 768 + 256 + dp];
        *(u16x8*)&Kb[row * 32 + dp] = kv;
    }
    for (int idx = tid; idx < 224 * 32; idx += 256) {
        int row = idx >> 5, d = idx & 31;
        Vt[d * 232 + row] = (row < 196) ? qg[(size_t)row * 768 + 512 + d] : (u16)0;
    }
    for (int c = lane; c < 16 * 24; c += 64) {
        int m = c / 24, cc = 208 + (c % 24);
        Pl[wave][m * 232 + cc] = 0;
    }
    __syncthreads();

    for (int t = wave; t < 13; t += 4) {
        const int m0 = t * 16;
        bf16x8 aq = {};
        const int qrow = m0 + l16;
        if (qrow < 196) aq = *(const bf16x8*)&qg[(size_t)qrow * 768 + quad * 8];

        f32x4 s[13];
        #pragma unroll
        for (int ct = 0; ct < 13; ct++) {
            bf16x8 bk = *(const bf16x8*)&Kb[(ct * 16 + l16) * 32 + quad * 8];
            s[ct] = __builtin_amdgcn_mfma_f32_16x16x32_bf16(aq, bk, (f32x4){0.f, 0.f, 0.f, 0.f}, 0, 0, 0);
        }
        if (l16 >= 4) {
            #pragma unroll
            for (int r = 0; r < 4; r++) s[12][r] = -1e30f;
        }
        float mx[4] = {-1e30f, -1e30f, -1e30f, -1e30f};
        #pragma unroll
        for (int ct = 0; ct < 13; ct++)
            #pragma unroll
            for (int r = 0; r < 4; r++) mx[r] = fmaxf(mx[r], s[ct][r]);
        #pragma unroll
        for (int off = 1; off < 16; off <<= 1)
            #pragma unroll
            for (int r = 0; r < 4; r++) mx[r] = fmaxf(mx[r], __shfl_xor(mx[r], off, 64));
        float sum[4] = {0.f, 0.f, 0.f, 0.f};
        #pragma unroll
        for (int ct = 0; ct < 13; ct++) {
            #pragma unroll
            for (int r = 0; r < 4; r++) {
                float p = __expf((s[ct][r] - mx[r]) * scale);
                sum[r] += p;
                Pl[wave][(quad * 4 + r) * 232 + ct * 16 + l16] = f2b(p);
            }
        }
        #pragma unroll
        for (int off = 1; off < 16; off <<= 1)
            #pragma unroll
            for (int r = 0; r < 4; r++) sum[r] += __shfl_xor(sum[r], off, 64);
        float inv[4];
        #pragma unroll
        for (int r = 0; r < 4; r++) inv[r] = 1.f / sum[r];

        #pragma unroll
        for (int nt = 0; nt < 2; nt++) {
            f32x4 ao = {0.f, 0.f, 0.f, 0.f};
            #pragma unroll
            for (int kc = 0; kc < 7; kc++) {
                bf16x8 ap = *(const bf16x8*)&Pl[wave][l16 * 232 + kc * 32 + quad * 8];
                bf16x8 bv = *(const bf16x8*)&Vt[(nt * 16 + l16) * 232 + kc * 32 + quad * 8];
                ao = __builtin_amdgcn_mfma_f32_16x16x32_bf16(ap, bv, ao, 0, 0, 0);
            }
            #pragma unroll
            for (int r = 0; r < 4; r++) {
                const int gm = m0 + quad * 4 + r;
                if (gm < 196)
                    o[((size_t)b * 196 + gm) * 256 + h * 32 + nt * 16 + l16] = f2b(ao[r] * inv[r]);
            }
        }
    }
}

// ---------------------------------------------------------------------------
extern "C" void kernel_launch(void* const* d_in, const int* in_sizes, int n_in,
                              void* d_out, int out_size, void* d_ws, size_t ws_size,
                              hipStream_t stream) {
    // All inputs are float32 per the reference's setup_inputs().
    const float* x      = (const float*)d_in[0];
    const float* Wqkv   = (const float*)d_in[1];
    const float* bqkv   = (const float*)d_in[2];
    const float* Wproj  = (const float*)d_in[3];
    const float* bproj  = (const float*)d_in[4];
    const float* W1     = (const float*)d_in[5];
    const float* b1     = (const float*)d_in[6];
    const float* W2     = (const float*)d_in[7];
    const float* b2     = (const float*)d_in[8];
    const float* saw    = (const float*)d_in[9];
    const float* sab    = (const float*)d_in[10];
    const float* alpha1 = (const float*)d_in[11];
    const float* g1     = (const float*)d_in[12];
    const float* be1    = (const float*)d_in[13];
    const float* rm1    = (const float*)d_in[14];
    const float* rv1    = (const float*)d_in[15];
    const float* alpha2 = (const float*)d_in[16];
    const float* g2     = (const float*)d_in[17];
    const float* be2    = (const float*)d_in[18];
    const float* rm2    = (const float*)d_in[19];
    const float* rv2    = (const float*)d_in[20];

    const int B = 256, Cc = 256, Np = 196, CM = 2048;
    const int M = B * Np; // 50176

    auto al = [](size_t s) { return (s + 255) & ~(size_t)255; };
    char* ws = (char*)d_ws;
    const size_t o_t0  = 0;
    const size_t o_t1  = o_t0 + al((size_t)M * Cc * 2);
    const size_t o_wq  = o_t1 + al((size_t)M * Cc * 2);
    const size_t o_wp  = o_wq + al((size_t)768 * Cc * 2);
    const size_t o_w1  = o_wp + al((size_t)Cc * Cc * 2);
    const size_t o_w2  = o_w1 + al((size_t)Cc * CM * 2);
    const size_t o_scr = o_w2 + al((size_t)CM * Cc * 2);
    const size_t S = (ws_size > o_scr) ? ws_size - o_scr : 0;

    u16* t0     = (u16*)(ws + o_t0);
    u16* t1b    = (u16*)(ws + o_t1);
    u16* WqkvT  = (u16*)(ws + o_wq);
    u16* WprojT = (u16*)(ws + o_wp);
    u16* W1T    = (u16*)(ws + o_w1);
    u16* W2T    = (u16*)(ws + o_w2);
    u16* scr    = (u16*)(ws + o_scr);
    u16* t2     = t0;            // alias: t0 dead after proj epilogue
    u16* obuf   = (u16*)d_out;   // bf16 scratch in f32 d_out; fully rewritten by final btrans
    float* out  = (float*)d_out;

    // chunk counts: row counts stay multiples of 128; nq | 256 (attn batches), nf | 392
    int nq = 1; while (nq < 8 && ((size_t)(M / nq) * 768 * 2) > S) nq *= 2;
    const int nf_opts[7] = {1, 2, 4, 8, 14, 28, 56};
    int nf = 56;
    for (int i = 0; i < 7; ++i) {
        if (((size_t)(M / nf_opts[i]) * CM * 2) <= S) { nf = nf_opts[i]; break; }
    }
    const int Mq = M / nq, Bq = B / nq;
    const int Mf = M / nf;

    dim3 tb(32, 8, 1);
    // x f32 [B][C][N] -> t0 bf16 [B][N][C]
    btrans_f2b<<<dim3((Np + 31) / 32, (Cc + 31) / 32, B), tb, 0, stream>>>(x, t0, Cc, Np);
    // weights f32 [K][N] -> bf16 [N][K]
    btrans_f2b<<<dim3(768 / 32, Cc / 32, 1), tb, 0, stream>>>(Wqkv,  WqkvT,  Cc, 768);
    btrans_f2b<<<dim3(Cc  / 32, Cc / 32, 1), tb, 0, stream>>>(Wproj, WprojT, Cc, Cc);
    btrans_f2b<<<dim3(CM  / 32, Cc / 32, 1), tb, 0, stream>>>(W1,    W1T,    Cc, CM);
    btrans_f2b<<<dim3(Cc  / 32, CM / 32, 1), tb, 0, stream>>>(W2,    W2T,    CM, Cc);

    // qkv + attention, chunked over batches
    for (int c = 0; c < nq; ++c) {
        gemm_bt<0><<<dim3(768 / 128, Mq / 128), 256, 0, stream>>>(
            t0 + (size_t)c * Mq * Cc, WqkvT, bqkv, scr, Mq, 768, Cc, 0,
            nullptr, nullptr, nullptr, nullptr, nullptr, nullptr, nullptr, nullptr);
        attn_kernel<<<dim3(Bq * 8), 256, 0, stream>>>(scr, obuf + (size_t)c * Mq * Cc);
    }

    // t1 = RepBN1(t0 + obuf @ Wproj + bproj)
    gemm_bt<1><<<dim3(Cc / 128, M / 128), 256, 0, stream>>>(
        obuf, WprojT, bproj, t1b, M, Cc, Cc, 0,
        t0, g1, be1, rm1, rv1, alpha1, nullptr, nullptr);

    // FFN, chunked over rows
    for (int c = 0; c < nf; ++c) {
        gemm_bt<2><<<dim3(CM / 128, Mf / 128), 256, 0, stream>>>(
            t1b + (size_t)c * Mf * Cc, W1T, b1, scr, Mf, CM, Cc, c * Mf,
            nullptr, nullptr, nullptr, nullptr, nullptr, nullptr, saw, sab);
        gemm_bt<1><<<dim3(Cc / 128, Mf / 128), 256, 0, stream>>>(
            scr, W2T, b2, t2 + (size_t)c * Mf * Cc, Mf, Cc, CM, 0,
            t1b + (size_t)c * Mf * Cc, g2, be2, rm2, rv2, alpha2, nullptr, nullptr);
    }

    // t2 bf16 [B][N][C] -> out f32 [B][C][N]
    btrans_b2f<<<dim3((Cc + 31) / 32, (Np + 31) / 32, B), tb, 0, stream>>>(t2, out, Np, Cc);
}